// Round 4
// baseline (3810.416 us; speedup 1.0000x reference)
//
#include <hip/hip_runtime.h>

// NonLocalMeans: rgb (8,3,1024,1024) f32, search 11x11, patch 5x5, circular.
// out(p) = sum_s w(p,s)*rgb(p-s) / sum_s w(p,s),
// w(p,s) = exp(-sqrt(box5x5((y - y_shift)^2)) * inv_h)
//
// R4 = R3 (expand-the-square: box((y-y')^2) = A(p)+A(p-s)-2*cross, A in
// ldsC.w) + dx-window split to fit the 64-VGPR cap BY CONSTRUCTION.
// Evidence: VGPR_Count pinned at 64 across 4 structures and 2 attributes;
// WRITE_SIZE = spill-o-meter showed ~17 floats/thread/dy spilled with the
// 44-partial ladder (1.7 GB scratch writes). Split J=0..5 / J=6..10 ->
// peak partials 24 -> live ~60-64.
// NOT repeating R2's mistakes: partials stay block-scoped per pass, single
// float4 LDS array (one base pointer + imm offsets), straight row loads
// (no register rotation). Per-accumulator addition order unchanged
// (dy asc; J asc within dy) -> bit-identical output.

#define HW (1024 * 1024)
#define W 1024
#define MASK 1023

constexpr int TILE = 32;
constexpr int YREG = 46;    // TILE + 2*7 (shift 5 + patch 2)
constexpr int YPITCH = 48;
constexpr int CREG = 42;    // TILE + 2*5
// -log2(e) / (1.0 + 1e-6)
constexpr float NEG_C = -1.4426935981939074f;

// 5-tap cross-correlation; c0..c4 in scope at expansion site
#define CR5(W0,W1,W2,W3,W4) \
    fmaf(c4,(W4), fmaf(c3,(W3), fmaf(c2,(W2), fmaf(c1,(W1), c0*(W0)))))

// h_J = 5-tap correlation over ywp[10-J .. 14-J].
// Pass A covers J=0..5 (needs ywp[5..14]); pass B covers J=6..10 (ywp[0..8]).
// yci/ywi are per-dy scalar LDS indices; RR*YPITCH folds into ds_read imms.
// NOT do-while wrapped: h values must stay in scope for VSET/VADD.
#define ROW_HA(RR)                                                          \
    const float* ycp = &ldsY[yci + (RR) * YPITCH];                          \
    const float* ywp = &ldsY[ywi + (RR) * YPITCH];                          \
    const float c0=ycp[0],c1=ycp[1],c2=ycp[2],c3=ycp[3],c4=ycp[4];          \
    const float w5 =ywp[5], w6 =ywp[6], w7 =ywp[7], w8 =ywp[8], w9 =ywp[9]; \
    const float w10=ywp[10],w11=ywp[11],w12=ywp[12],w13=ywp[13],w14=ywp[14];\
    const float h0 = CR5(w10,w11,w12,w13,w14);                              \
    const float h1 = CR5(w9, w10,w11,w12,w13);                              \
    const float h2 = CR5(w8, w9, w10,w11,w12);                              \
    const float h3 = CR5(w7, w8, w9, w10,w11);                              \
    const float h4 = CR5(w6, w7, w8, w9, w10);                              \
    const float h5 = CR5(w5, w6, w7, w8, w9);

#define ROW_HB(RR)                                                          \
    const float* ycp = &ldsY[yci + (RR) * YPITCH];                          \
    const float* ywp = &ldsY[ywi + (RR) * YPITCH];                          \
    const float c0=ycp[0],c1=ycp[1],c2=ycp[2],c3=ycp[3],c4=ycp[4];          \
    const float w0 =ywp[0], w1 =ywp[1], w2 =ywp[2], w3 =ywp[3], w4 =ywp[4]; \
    const float w5 =ywp[5], w6 =ywp[6], w7 =ywp[7], w8 =ywp[8];             \
    const float h6  = CR5(w4, w5, w6, w7, w8);                              \
    const float h7  = CR5(w3, w4, w5, w6, w7);                              \
    const float h8  = CR5(w2, w3, w4, w5, w6);                              \
    const float h9  = CR5(w1, w2, w3, w4, w5);                              \
    const float h10 = CR5(w0, w1, w2, w3, w4);

// per-pass vertical partials, named scalars, block-scoped
#define VDECLA(VD) float VD##_0, VD##_1, VD##_2, VD##_3, VD##_4, VD##_5
#define VSETA(VD)  VD##_0 =h0; VD##_1 =h1; VD##_2 =h2;                      \
                   VD##_3 =h3; VD##_4 =h4; VD##_5 =h5
#define VADDA(VD)  VD##_0+=h0; VD##_1+=h1; VD##_2+=h2;                      \
                   VD##_3+=h3; VD##_4+=h4; VD##_5+=h5
#define VDECLB(VD) float VD##_6, VD##_7, VD##_8, VD##_9, VD##_10
#define VSETB(VD)  VD##_6 =h6; VD##_7 =h7; VD##_8 =h8;                      \
                   VD##_9 =h9; VD##_10=h10
#define VADDB(VD)  VD##_6+=h6; VD##_7+=h7; VD##_8+=h8;                      \
                   VD##_9+=h9; VD##_10+=h10

// finalize one (YO,J): S = Ac + Aw - 2*cross, clamp, sqrt, exp2, accumulate
#define FIN1(YO, VD, J) do {                                                \
    float4 px = ldsC[cri + (YO) * CREG - (J)];                              \
    float s = fmaf(-2.0f, VD##_##J, ldsC[abi + (YO) * CREG].w + px.w);      \
    s = fmaxf(s, 0.0f);                                                     \
    float dist = __builtin_amdgcn_sqrtf(s);                                 \
    float wgt  = __builtin_amdgcn_exp2f(dist * NEG_C);                      \
    aR##YO = fmaf(wgt, px.x, aR##YO);                                       \
    aG##YO = fmaf(wgt, px.y, aG##YO);                                       \
    aB##YO = fmaf(wgt, px.z, aB##YO);                                       \
    aW##YO += wgt;                                                          \
} while (0)

#define FIN_A(YO, VD) do {                                                  \
    FIN1(YO,VD,0); FIN1(YO,VD,1); FIN1(YO,VD,2);                            \
    FIN1(YO,VD,3); FIN1(YO,VD,4); FIN1(YO,VD,5);                            \
} while (0)

#define FIN_B(YO, VD) do {                                                  \
    FIN1(YO,VD,6); FIN1(YO,VD,7); FIN1(YO,VD,8);                            \
    FIN1(YO,VD,9); FIN1(YO,VD,10);                                          \
} while (0)

#define STORE(YO) do {                                                      \
    const int off = (by0 + y0 + (YO)) * W + bx0 + tx;                       \
    const float inv = 1.0f / aW##YO;                                        \
    obase[off]          = aR##YO * inv;                                     \
    obase[off + HW]     = aG##YO * inv;                                     \
    obase[off + 2 * HW] = aB##YO * inv;                                     \
} while (0)

// squared 5-tap row sum for the A-field precompute
#define A5(p) fmaf((p)[4],(p)[4], fmaf((p)[3],(p)[3], fmaf((p)[2],(p)[2],   \
              fmaf((p)[1],(p)[1], (p)[0]*(p)[0]))))

__global__ void __launch_bounds__(256) __attribute__((amdgpu_waves_per_eu(4, 4)))
nlm_fused(const float* __restrict__ rgb, float* __restrict__ out) {
    __shared__ float  ldsY[YREG * YPITCH];      // 8832 B
    __shared__ float4 ldsC[CREG * CREG];        // 28224 B  (.w = box5x5(y^2))

    const int tid = threadIdx.x;
    const int batch = blockIdx.z;
    const int by0 = blockIdx.y * TILE;
    const int bx0 = blockIdx.x * TILE;

    const float* base = rgb + (size_t)batch * 3 * HW;

    // ---- stage luminance tile (mean over channels), halo 7 ----
    for (int i = tid; i < YREG * YREG; i += 256) {
        int ry = i / YREG, rx = i - ry * YREG;
        int gy = (by0 + ry - 7) & MASK;
        int gx = (bx0 + rx - 7) & MASK;
        int off = gy * W + gx;
        float v = (base[off] + base[off + HW] + base[off + 2 * HW]) * (1.0f / 3.0f);
        ldsY[ry * YPITCH + rx] = v;
    }
    __syncthreads();    // Y complete before A-field compute

    // ---- stage rgb tile as float4 (halo 5), .w = A = box5x5(y^2) ----
    for (int i = tid; i < CREG * CREG; i += 256) {
        int ry = i / CREG, rx = i - ry * CREG;
        int gy = (by0 + ry - 5) & MASK;
        int gx = (bx0 + rx - 5) & MASK;
        int off = gy * W + gx;
        const float* yb = &ldsY[ry * YPITCH + rx];   // A window = Y rows ry..ry+4
        float a =  A5(yb);
        a += A5(yb + YPITCH);
        a += A5(yb + 2 * YPITCH);
        a += A5(yb + 3 * YPITCH);
        a += A5(yb + 4 * YPITCH);
        ldsC[i] = make_float4(base[off], base[off + HW], base[off + 2 * HW], a);
    }
    __syncthreads();

    const int tx = tid & 31;          // output column within tile
    const int y0 = (tid >> 5) * 4;    // 4-pixel column run per thread

    // loop-invariant scalar LDS indices (offsets fold into ds_read imms)
    const int yci = (y0 + 5) * YPITCH + tx + 5;   // center rows, +RR*YPITCH
    const int abi = (y0 + 5) * CREG + tx + 5;     // A(center),  +YO*CREG

    float aR0=0.f, aG0=0.f, aB0=0.f, aW0=0.f;
    float aR1=0.f, aG1=0.f, aB1=0.f, aW1=0.f;
    float aR2=0.f, aG2=0.f, aB2=0.f, aW2=0.f;
    float aR3=0.f, aG3=0.f, aB3=0.f, aW3=0.f;

    #pragma clang loop unroll(disable)
    for (int dy = -5; dy <= 5; ++dy) {
        const int ywi = (y0 + 5 - dy) * YPITCH + tx;      // +RR*YPITCH
        const int cri = (y0 - dy + 5) * CREG + tx + 10;   // +YO*CREG - J
        {   // ---- pass A: J = 0..5 (dx = -5..0) ----
            VDECLA(v0); VDECLA(v1); VDECLA(v2); VDECLA(v3);
            { ROW_HA(0); VSETA(v0); }
            { ROW_HA(1); VADDA(v0); VSETA(v1); }
            { ROW_HA(2); VADDA(v0); VADDA(v1); VSETA(v2); }
            { ROW_HA(3); VADDA(v0); VADDA(v1); VADDA(v2); VSETA(v3); }
            { ROW_HA(4); VADDA(v0); VADDA(v1); VADDA(v2); VADDA(v3); }
            FIN_A(0, v0);
            { ROW_HA(5); VADDA(v1); VADDA(v2); VADDA(v3); }
            FIN_A(1, v1);
            { ROW_HA(6); VADDA(v2); VADDA(v3); }
            FIN_A(2, v2);
            { ROW_HA(7); VADDA(v3); }
            FIN_A(3, v3);
        }
        {   // ---- pass B: J = 6..10 (dx = 1..5) ----
            VDECLB(v0); VDECLB(v1); VDECLB(v2); VDECLB(v3);
            { ROW_HB(0); VSETB(v0); }
            { ROW_HB(1); VADDB(v0); VSETB(v1); }
            { ROW_HB(2); VADDB(v0); VADDB(v1); VSETB(v2); }
            { ROW_HB(3); VADDB(v0); VADDB(v1); VADDB(v2); VSETB(v3); }
            { ROW_HB(4); VADDB(v0); VADDB(v1); VADDB(v2); VADDB(v3); }
            FIN_B(0, v0);
            { ROW_HB(5); VADDB(v1); VADDB(v2); VADDB(v3); }
            FIN_B(1, v1);
            { ROW_HB(6); VADDB(v2); VADDB(v3); }
            FIN_B(2, v2);
            { ROW_HB(7); VADDB(v3); }
            FIN_B(3, v3);
        }
    }

    float* obase = out + (size_t)batch * 3 * HW;
    STORE(0);
    STORE(1);
    STORE(2);
    STORE(3);
}

extern "C" void kernel_launch(void* const* d_in, const int* in_sizes, int n_in,
                              void* d_out, int out_size, void* d_ws, size_t ws_size,
                              hipStream_t stream) {
    const float* rgb = (const float*)d_in[0];
    float* out = (float*)d_out;
    dim3 grid(W / TILE, W / TILE, 8);
    dim3 block(256, 1, 1);
    hipLaunchKernelGGL(nlm_fused, grid, block, 0, stream, rgb, out);
}

// Round 5
// 782.908 us; speedup vs baseline: 4.8670x; 4.8670x over previous
//
#include <hip/hip_runtime.h>

// NonLocalMeans: rgb (8,3,1024,1024) f32, search 11x11, patch 5x5, circular.
// out(p) = sum_s w(p,s)*rgb(p-s) / sum_s w(p,s),
// w(p,s) = exp(-sqrt(box5x5((y - y_shift)^2)) * inv_h)
//
// R5 = R4 (expand-the-square + dx-split so in-order peak live ~59 < 64 VGPR)
// + __builtin_amdgcn_sched_barrier(0) fences after EVERY row/FIN block.
// Mechanism (R2/R4 post-mortem): the two per-dy passes are independent
// instruction streams; the pre-RA scheduler interleaved them and hoisted
// pass-B ds_reads above pass-A FINs, rebuilding a >90-reg live set ->
// catastrophic spill (WRITE 9.5 GB, 5.7x R1). Fences make source order =
// schedule order, so the designed live set is the allocated live set.
// WRITE_SIZE is the spill-o-meter: output-only is ~0.11e6 KB.
// Accumulation order (dy asc; per YO: J 0..5 then 6..10) identical to
// R3/R4 (both passed, absmax 0.00390625) -> bit-identical output.

#define HW (1024 * 1024)
#define W 1024
#define MASK 1023

constexpr int TILE = 32;
constexpr int YREG = 46;    // TILE + 2*7 (shift 5 + patch 2)
constexpr int YPITCH = 48;
constexpr int CREG = 42;    // TILE + 2*5
// -log2(e) / (1.0 + 1e-6)
constexpr float NEG_C = -1.4426935981939074f;

#define SBAR() __builtin_amdgcn_sched_barrier(0)

// 5-tap cross-correlation; c0..c4 in scope at expansion site
#define CR5(W0,W1,W2,W3,W4) \
    fmaf(c4,(W4), fmaf(c3,(W3), fmaf(c2,(W2), fmaf(c1,(W1), c0*(W0)))))

// h_J = 5-tap correlation over ywp[10-J .. 14-J].
// Pass A: J=0..5 (ywp[5..14]); pass B: J=6..10 (ywp[0..8]).
// yci/ywi are per-dy scalar indices; RR*YPITCH folds into ds_read imms.
#define ROW_HA(RR)                                                          \
    const float* ycp = &ldsY[yci + (RR) * YPITCH];                          \
    const float* ywp = &ldsY[ywi + (RR) * YPITCH];                          \
    const float c0=ycp[0],c1=ycp[1],c2=ycp[2],c3=ycp[3],c4=ycp[4];          \
    const float w5 =ywp[5], w6 =ywp[6], w7 =ywp[7], w8 =ywp[8], w9 =ywp[9]; \
    const float w10=ywp[10],w11=ywp[11],w12=ywp[12],w13=ywp[13],w14=ywp[14];\
    const float h0 = CR5(w10,w11,w12,w13,w14);                              \
    const float h1 = CR5(w9, w10,w11,w12,w13);                              \
    const float h2 = CR5(w8, w9, w10,w11,w12);                              \
    const float h3 = CR5(w7, w8, w9, w10,w11);                              \
    const float h4 = CR5(w6, w7, w8, w9, w10);                              \
    const float h5 = CR5(w5, w6, w7, w8, w9);

#define ROW_HB(RR)                                                          \
    const float* ycp = &ldsY[yci + (RR) * YPITCH];                          \
    const float* ywp = &ldsY[ywi + (RR) * YPITCH];                          \
    const float c0=ycp[0],c1=ycp[1],c2=ycp[2],c3=ycp[3],c4=ycp[4];          \
    const float w0 =ywp[0], w1 =ywp[1], w2 =ywp[2], w3 =ywp[3], w4 =ywp[4]; \
    const float w5 =ywp[5], w6 =ywp[6], w7 =ywp[7], w8 =ywp[8];             \
    const float h6  = CR5(w4, w5, w6, w7, w8);                              \
    const float h7  = CR5(w3, w4, w5, w6, w7);                              \
    const float h8  = CR5(w2, w3, w4, w5, w6);                              \
    const float h9  = CR5(w1, w2, w3, w4, w5);                              \
    const float h10 = CR5(w0, w1, w2, w3, w4);

// per-pass vertical partials, named scalars, block-scoped
#define VDECLA(VD) float VD##_0, VD##_1, VD##_2, VD##_3, VD##_4, VD##_5
#define VSETA(VD)  VD##_0 =h0; VD##_1 =h1; VD##_2 =h2;                      \
                   VD##_3 =h3; VD##_4 =h4; VD##_5 =h5
#define VADDA(VD)  VD##_0+=h0; VD##_1+=h1; VD##_2+=h2;                      \
                   VD##_3+=h3; VD##_4+=h4; VD##_5+=h5
#define VDECLB(VD) float VD##_6, VD##_7, VD##_8, VD##_9, VD##_10
#define VSETB(VD)  VD##_6 =h6; VD##_7 =h7; VD##_8 =h8;                      \
                   VD##_9 =h9; VD##_10=h10
#define VADDB(VD)  VD##_6+=h6; VD##_7+=h7; VD##_8+=h8;                      \
                   VD##_9+=h9; VD##_10+=h10

// finalize one (YO,J): S = Ac + Aw - 2*cross, clamp, sqrt, exp2, accumulate
#define FIN1(YO, VD, J) do {                                                \
    float4 px = crow[-(J)];                                                 \
    float s = fmaf(-2.0f, VD##_##J, acb + px.w);                            \
    s = fmaxf(s, 0.0f);                                                     \
    float dist = __builtin_amdgcn_sqrtf(s);                                 \
    float wgt  = __builtin_amdgcn_exp2f(dist * NEG_C);                      \
    aR##YO = fmaf(wgt, px.x, aR##YO);                                       \
    aG##YO = fmaf(wgt, px.y, aG##YO);                                       \
    aB##YO = fmaf(wgt, px.z, aB##YO);                                       \
    aW##YO += wgt;                                                          \
} while (0)

#define FIN_A(YO, VD) do {                                                  \
    const float4* crow = &ldsC[cri + (YO) * CREG];                          \
    const float acb = ldsC[abi + (YO) * CREG].w;                            \
    FIN1(YO,VD,0); FIN1(YO,VD,1); FIN1(YO,VD,2);                            \
    FIN1(YO,VD,3); FIN1(YO,VD,4); FIN1(YO,VD,5);                            \
} while (0)

#define FIN_B(YO, VD) do {                                                  \
    const float4* crow = &ldsC[cri + (YO) * CREG];                          \
    const float acb = ldsC[abi + (YO) * CREG].w;                            \
    FIN1(YO,VD,6); FIN1(YO,VD,7); FIN1(YO,VD,8);                            \
    FIN1(YO,VD,9); FIN1(YO,VD,10);                                          \
} while (0)

#define STORE(YO) do {                                                      \
    const int off = (by0 + y0 + (YO)) * W + bx0 + tx;                       \
    const float inv = 1.0f / aW##YO;                                        \
    obase[off]          = aR##YO * inv;                                     \
    obase[off + HW]     = aG##YO * inv;                                     \
    obase[off + 2 * HW] = aB##YO * inv;                                     \
} while (0)

// squared 5-tap row sum for the A-field precompute
#define A5(p) fmaf((p)[4],(p)[4], fmaf((p)[3],(p)[3], fmaf((p)[2],(p)[2],   \
              fmaf((p)[1],(p)[1], (p)[0]*(p)[0]))))

__global__ void __launch_bounds__(256) __attribute__((amdgpu_waves_per_eu(4, 4)))
nlm_fused(const float* __restrict__ rgb, float* __restrict__ out) {
    __shared__ float  ldsY[YREG * YPITCH];      // 8832 B
    __shared__ float4 ldsC[CREG * CREG];        // 28224 B  (.w = box5x5(y^2))

    const int tid = threadIdx.x;
    const int batch = blockIdx.z;
    const int by0 = blockIdx.y * TILE;
    const int bx0 = blockIdx.x * TILE;

    const float* base = rgb + (size_t)batch * 3 * HW;

    // ---- stage luminance tile (mean over channels), halo 7 ----
    for (int i = tid; i < YREG * YREG; i += 256) {
        int ry = i / YREG, rx = i - ry * YREG;
        int gy = (by0 + ry - 7) & MASK;
        int gx = (bx0 + rx - 7) & MASK;
        int off = gy * W + gx;
        float v = (base[off] + base[off + HW] + base[off + 2 * HW]) * (1.0f / 3.0f);
        ldsY[ry * YPITCH + rx] = v;
    }
    __syncthreads();    // Y complete before A-field compute

    // ---- stage rgb tile as float4 (halo 5), .w = A = box5x5(y^2) ----
    for (int i = tid; i < CREG * CREG; i += 256) {
        int ry = i / CREG, rx = i - ry * CREG;
        int gy = (by0 + ry - 5) & MASK;
        int gx = (bx0 + rx - 5) & MASK;
        int off = gy * W + gx;
        const float* yb = &ldsY[ry * YPITCH + rx];   // A window = Y rows ry..ry+4
        float a =  A5(yb);
        a += A5(yb + YPITCH);
        a += A5(yb + 2 * YPITCH);
        a += A5(yb + 3 * YPITCH);
        a += A5(yb + 4 * YPITCH);
        ldsC[i] = make_float4(base[off], base[off + HW], base[off + 2 * HW], a);
    }
    __syncthreads();

    const int tx = tid & 31;          // output column within tile
    const int y0 = (tid >> 5) * 4;    // 4-pixel column run per thread

    // loop-invariant scalar LDS indices (offsets fold into ds_read imms)
    const int yci = (y0 + 5) * YPITCH + tx + 5;   // center rows, +RR*YPITCH
    const int abi = (y0 + 5) * CREG + tx + 5;     // A(center),  +YO*CREG

    float aR0=0.f, aG0=0.f, aB0=0.f, aW0=0.f;
    float aR1=0.f, aG1=0.f, aB1=0.f, aW1=0.f;
    float aR2=0.f, aG2=0.f, aB2=0.f, aW2=0.f;
    float aR3=0.f, aG3=0.f, aB3=0.f, aW3=0.f;

    #pragma clang loop unroll(disable)
    for (int dy = -5; dy <= 5; ++dy) {
        const int ywi = (y0 + 5 - dy) * YPITCH + tx;      // +RR*YPITCH
        const int cri = (y0 - dy + 5) * CREG + tx + 10;   // +YO*CREG - J
        {   // ---- pass A: J = 0..5 (dx = -5..0) ----
            VDECLA(v0); VDECLA(v1); VDECLA(v2); VDECLA(v3);
            { ROW_HA(0); VSETA(v0); }                          SBAR();
            { ROW_HA(1); VADDA(v0); VSETA(v1); }               SBAR();
            { ROW_HA(2); VADDA(v0); VADDA(v1); VSETA(v2); }    SBAR();
            { ROW_HA(3); VADDA(v0); VADDA(v1); VADDA(v2); VSETA(v3); } SBAR();
            { ROW_HA(4); VADDA(v0); VADDA(v1); VADDA(v2); VADDA(v3); } SBAR();
            FIN_A(0, v0);                                      SBAR();
            { ROW_HA(5); VADDA(v1); VADDA(v2); VADDA(v3); }    SBAR();
            FIN_A(1, v1);                                      SBAR();
            { ROW_HA(6); VADDA(v2); VADDA(v3); }               SBAR();
            FIN_A(2, v2);                                      SBAR();
            { ROW_HA(7); VADDA(v3); }                          SBAR();
            FIN_A(3, v3);                                      SBAR();
        }
        {   // ---- pass B: J = 6..10 (dx = 1..5) ----
            VDECLB(v0); VDECLB(v1); VDECLB(v2); VDECLB(v3);
            { ROW_HB(0); VSETB(v0); }                          SBAR();
            { ROW_HB(1); VADDB(v0); VSETB(v1); }               SBAR();
            { ROW_HB(2); VADDB(v0); VADDB(v1); VSETB(v2); }    SBAR();
            { ROW_HB(3); VADDB(v0); VADDB(v1); VADDB(v2); VSETB(v3); } SBAR();
            { ROW_HB(4); VADDB(v0); VADDB(v1); VADDB(v2); VADDB(v3); } SBAR();
            FIN_B(0, v0);                                      SBAR();
            { ROW_HB(5); VADDB(v1); VADDB(v2); VADDB(v3); }    SBAR();
            FIN_B(1, v1);                                      SBAR();
            { ROW_HB(6); VADDB(v2); VADDB(v3); }               SBAR();
            FIN_B(2, v2);                                      SBAR();
            { ROW_HB(7); VADDB(v3); }                          SBAR();
            FIN_B(3, v3);                                      SBAR();
        }
    }

    float* obase = out + (size_t)batch * 3 * HW;
    STORE(0);
    STORE(1);
    STORE(2);
    STORE(3);
}

extern "C" void kernel_launch(void* const* d_in, const int* in_sizes, int n_in,
                              void* d_out, int out_size, void* d_ws, size_t ws_size,
                              hipStream_t stream) {
    const float* rgb = (const float*)d_in[0];
    float* out = (float*)d_out;
    dim3 grid(W / TILE, W / TILE, 8);
    dim3 block(256, 1, 1);
    hipLaunchKernelGGL(nlm_fused, grid, block, 0, stream, rgb, out);
}

// Round 6
// 777.198 us; speedup vs baseline: 4.9028x; 1.0073x over previous
//
#include <hip/hip_runtime.h>

// NonLocalMeans: rgb (8,3,1024,1024) f32, search 11x11, patch 5x5, circular.
// out(p) = sum_s w(p,s)*rgb(p-s) / sum_s w(p,s),
// w(p,s) = exp(-sqrt(box5x5((y - y_shift)^2)) * inv_h)
//
// R6 = R5 (expand-the-square + dx-split + sched_barrier(0) fences; WRITE_SIZE
// proved spill-free at VGPR=60, dur 783us) + three liveness-neutral VALU cuts:
//  1. Luminance pre-scaled by K = inv_h*log2(e) = 1.4426936 at staging.
//     Cross and A = box(y^2) then scale by K^2, so sqrt gives K*dist directly
//     -> the per-FIN1 `dist*NEG_C` mul is deleted (44 ops/dy).
//  2. wgt = exp2(-dist): neg is a free input modifier on v_exp_f32.
//  3. fmax(s,0) -> |s| (free abs modifier on v_sqrt_f32): s<0 only by
//     cancellation rounding (|s|<~1e-5) exactly when true S~0; sqrt(|s|)~0
//     -> w~1 = the correct limit.
// FIN1: 8 -> 6 regular VALU. Fences, loop structure, liveness identical to R5
// (one temp removed). WRITE_SIZE is the spill-o-meter: ~98e3 KB = output only.

#define HW (1024 * 1024)
#define W 1024
#define MASK 1023

constexpr int TILE = 32;
constexpr int YREG = 46;    // TILE + 2*7 (shift 5 + patch 2)
constexpr int YPITCH = 48;
constexpr int CREG = 42;    // TILE + 2*5
// (1/3 channel mean) * inv_h*log2(e); inv_h = 1/(1+1e-6)
constexpr float K3 = 1.4426935981939074f / 3.0f;

#define SBAR() __builtin_amdgcn_sched_barrier(0)

// 5-tap cross-correlation; c0..c4 in scope at expansion site
#define CR5(W0,W1,W2,W3,W4) \
    fmaf(c4,(W4), fmaf(c3,(W3), fmaf(c2,(W2), fmaf(c1,(W1), c0*(W0)))))

// h_J = 5-tap correlation over ywp[10-J .. 14-J].
// Pass A: J=0..5 (ywp[5..14]); pass B: J=6..10 (ywp[0..8]).
// yci/ywi are per-dy scalar indices; RR*YPITCH folds into ds_read imms.
#define ROW_HA(RR)                                                          \
    const float* ycp = &ldsY[yci + (RR) * YPITCH];                          \
    const float* ywp = &ldsY[ywi + (RR) * YPITCH];                          \
    const float c0=ycp[0],c1=ycp[1],c2=ycp[2],c3=ycp[3],c4=ycp[4];          \
    const float w5 =ywp[5], w6 =ywp[6], w7 =ywp[7], w8 =ywp[8], w9 =ywp[9]; \
    const float w10=ywp[10],w11=ywp[11],w12=ywp[12],w13=ywp[13],w14=ywp[14];\
    const float h0 = CR5(w10,w11,w12,w13,w14);                              \
    const float h1 = CR5(w9, w10,w11,w12,w13);                              \
    const float h2 = CR5(w8, w9, w10,w11,w12);                              \
    const float h3 = CR5(w7, w8, w9, w10,w11);                              \
    const float h4 = CR5(w6, w7, w8, w9, w10);                              \
    const float h5 = CR5(w5, w6, w7, w8, w9);

#define ROW_HB(RR)                                                          \
    const float* ycp = &ldsY[yci + (RR) * YPITCH];                          \
    const float* ywp = &ldsY[ywi + (RR) * YPITCH];                          \
    const float c0=ycp[0],c1=ycp[1],c2=ycp[2],c3=ycp[3],c4=ycp[4];          \
    const float w0 =ywp[0], w1 =ywp[1], w2 =ywp[2], w3 =ywp[3], w4 =ywp[4]; \
    const float w5 =ywp[5], w6 =ywp[6], w7 =ywp[7], w8 =ywp[8];             \
    const float h6  = CR5(w4, w5, w6, w7, w8);                              \
    const float h7  = CR5(w3, w4, w5, w6, w7);                              \
    const float h8  = CR5(w2, w3, w4, w5, w6);                              \
    const float h9  = CR5(w1, w2, w3, w4, w5);                              \
    const float h10 = CR5(w0, w1, w2, w3, w4);

// per-pass vertical partials, named scalars, block-scoped
#define VDECLA(VD) float VD##_0, VD##_1, VD##_2, VD##_3, VD##_4, VD##_5
#define VSETA(VD)  VD##_0 =h0; VD##_1 =h1; VD##_2 =h2;                      \
                   VD##_3 =h3; VD##_4 =h4; VD##_5 =h5
#define VADDA(VD)  VD##_0+=h0; VD##_1+=h1; VD##_2+=h2;                      \
                   VD##_3+=h3; VD##_4+=h4; VD##_5+=h5
#define VDECLB(VD) float VD##_6, VD##_7, VD##_8, VD##_9, VD##_10
#define VSETB(VD)  VD##_6 =h6; VD##_7 =h7; VD##_8 =h8;                      \
                   VD##_9 =h9; VD##_10=h10
#define VADDB(VD)  VD##_6+=h6; VD##_7+=h7; VD##_8+=h8;                      \
                   VD##_9+=h9; VD##_10+=h10

// finalize one (YO,J): S = Ac + Aw - 2*cross (all pre-scaled by K^2),
// dist = sqrt(|S|) = K*d, wgt = exp2(-dist); abs & neg are free modifiers.
#define FIN1(YO, VD, J) do {                                                \
    float4 px = crow[-(J)];                                                 \
    float s = fmaf(-2.0f, VD##_##J, acb + px.w);                            \
    float dist = __builtin_amdgcn_sqrtf(__builtin_fabsf(s));                \
    float wgt  = __builtin_amdgcn_exp2f(-dist);                             \
    aR##YO = fmaf(wgt, px.x, aR##YO);                                       \
    aG##YO = fmaf(wgt, px.y, aG##YO);                                       \
    aB##YO = fmaf(wgt, px.z, aB##YO);                                       \
    aW##YO += wgt;                                                          \
} while (0)

#define FIN_A(YO, VD) do {                                                  \
    const float4* crow = &ldsC[cri + (YO) * CREG];                          \
    const float acb = ldsC[abi + (YO) * CREG].w;                            \
    FIN1(YO,VD,0); FIN1(YO,VD,1); FIN1(YO,VD,2);                            \
    FIN1(YO,VD,3); FIN1(YO,VD,4); FIN1(YO,VD,5);                            \
} while (0)

#define FIN_B(YO, VD) do {                                                  \
    const float4* crow = &ldsC[cri + (YO) * CREG];                          \
    const float acb = ldsC[abi + (YO) * CREG].w;                            \
    FIN1(YO,VD,6); FIN1(YO,VD,7); FIN1(YO,VD,8);                            \
    FIN1(YO,VD,9); FIN1(YO,VD,10);                                          \
} while (0)

#define STORE(YO) do {                                                      \
    const int off = (by0 + y0 + (YO)) * W + bx0 + tx;                       \
    const float inv = 1.0f / aW##YO;                                        \
    obase[off]          = aR##YO * inv;                                     \
    obase[off + HW]     = aG##YO * inv;                                     \
    obase[off + 2 * HW] = aB##YO * inv;                                     \
} while (0)

// squared 5-tap row sum for the A-field precompute (y pre-scaled by K)
#define A5(p) fmaf((p)[4],(p)[4], fmaf((p)[3],(p)[3], fmaf((p)[2],(p)[2],   \
              fmaf((p)[1],(p)[1], (p)[0]*(p)[0]))))

__global__ void __launch_bounds__(256) __attribute__((amdgpu_waves_per_eu(4, 4)))
nlm_fused(const float* __restrict__ rgb, float* __restrict__ out) {
    __shared__ float  ldsY[YREG * YPITCH];      // 8832 B  (K-scaled luminance)
    __shared__ float4 ldsC[CREG * CREG];        // 28224 B (.w = K^2*box5x5(y^2))

    const int tid = threadIdx.x;
    const int batch = blockIdx.z;
    const int by0 = blockIdx.y * TILE;
    const int bx0 = blockIdx.x * TILE;

    const float* base = rgb + (size_t)batch * 3 * HW;

    // ---- stage K-scaled luminance tile (mean over channels), halo 7 ----
    for (int i = tid; i < YREG * YREG; i += 256) {
        int ry = i / YREG, rx = i - ry * YREG;
        int gy = (by0 + ry - 7) & MASK;
        int gx = (bx0 + rx - 7) & MASK;
        int off = gy * W + gx;
        float v = (base[off] + base[off + HW] + base[off + 2 * HW]) * K3;
        ldsY[ry * YPITCH + rx] = v;
    }
    __syncthreads();    // Y complete before A-field compute

    // ---- stage rgb tile as float4 (halo 5), .w = K^2 * box5x5(y^2) ----
    for (int i = tid; i < CREG * CREG; i += 256) {
        int ry = i / CREG, rx = i - ry * CREG;
        int gy = (by0 + ry - 5) & MASK;
        int gx = (bx0 + rx - 5) & MASK;
        int off = gy * W + gx;
        const float* yb = &ldsY[ry * YPITCH + rx];   // A window = Y rows ry..ry+4
        float a =  A5(yb);
        a += A5(yb + YPITCH);
        a += A5(yb + 2 * YPITCH);
        a += A5(yb + 3 * YPITCH);
        a += A5(yb + 4 * YPITCH);
        ldsC[i] = make_float4(base[off], base[off + HW], base[off + 2 * HW], a);
    }
    __syncthreads();

    const int tx = tid & 31;          // output column within tile
    const int y0 = (tid >> 5) * 4;    // 4-pixel column run per thread

    // loop-invariant scalar LDS indices (offsets fold into ds_read imms)
    const int yci = (y0 + 5) * YPITCH + tx + 5;   // center rows, +RR*YPITCH
    const int abi = (y0 + 5) * CREG + tx + 5;     // A(center),  +YO*CREG

    float aR0=0.f, aG0=0.f, aB0=0.f, aW0=0.f;
    float aR1=0.f, aG1=0.f, aB1=0.f, aW1=0.f;
    float aR2=0.f, aG2=0.f, aB2=0.f, aW2=0.f;
    float aR3=0.f, aG3=0.f, aB3=0.f, aW3=0.f;

    #pragma clang loop unroll(disable)
    for (int dy = -5; dy <= 5; ++dy) {
        const int ywi = (y0 + 5 - dy) * YPITCH + tx;      // +RR*YPITCH
        const int cri = (y0 - dy + 5) * CREG + tx + 10;   // +YO*CREG - J
        {   // ---- pass A: J = 0..5 (dx = -5..0) ----
            VDECLA(v0); VDECLA(v1); VDECLA(v2); VDECLA(v3);
            { ROW_HA(0); VSETA(v0); }                          SBAR();
            { ROW_HA(1); VADDA(v0); VSETA(v1); }               SBAR();
            { ROW_HA(2); VADDA(v0); VADDA(v1); VSETA(v2); }    SBAR();
            { ROW_HA(3); VADDA(v0); VADDA(v1); VADDA(v2); VSETA(v3); } SBAR();
            { ROW_HA(4); VADDA(v0); VADDA(v1); VADDA(v2); VADDA(v3); } SBAR();
            FIN_A(0, v0);                                      SBAR();
            { ROW_HA(5); VADDA(v1); VADDA(v2); VADDA(v3); }    SBAR();
            FIN_A(1, v1);                                      SBAR();
            { ROW_HA(6); VADDA(v2); VADDA(v3); }               SBAR();
            FIN_A(2, v2);                                      SBAR();
            { ROW_HA(7); VADDA(v3); }                          SBAR();
            FIN_A(3, v3);                                      SBAR();
        }
        {   // ---- pass B: J = 6..10 (dx = 1..5) ----
            VDECLB(v0); VDECLB(v1); VDECLB(v2); VDECLB(v3);
            { ROW_HB(0); VSETB(v0); }                          SBAR();
            { ROW_HB(1); VADDB(v0); VSETB(v1); }               SBAR();
            { ROW_HB(2); VADDB(v0); VADDB(v1); VSETB(v2); }    SBAR();
            { ROW_HB(3); VADDB(v0); VADDB(v1); VADDB(v2); VSETB(v3); } SBAR();
            { ROW_HB(4); VADDB(v0); VADDB(v1); VADDB(v2); VADDB(v3); } SBAR();
            FIN_B(0, v0);                                      SBAR();
            { ROW_HB(5); VADDB(v1); VADDB(v2); VADDB(v3); }    SBAR();
            FIN_B(1, v1);                                      SBAR();
            { ROW_HB(6); VADDB(v2); VADDB(v3); }               SBAR();
            FIN_B(2, v2);                                      SBAR();
            { ROW_HB(7); VADDB(v3); }                          SBAR();
            FIN_B(3, v3);                                      SBAR();
        }
    }

    float* obase = out + (size_t)batch * 3 * HW;
    STORE(0);
    STORE(1);
    STORE(2);
    STORE(3);
}

extern "C" void kernel_launch(void* const* d_in, const int* in_sizes, int n_in,
                              void* d_out, int out_size, void* d_ws, size_t ws_size,
                              hipStream_t stream) {
    const float* rgb = (const float*)d_in[0];
    float* out = (float*)d_out;
    dim3 grid(W / TILE, W / TILE, 8);
    dim3 block(256, 1, 1);
    hipLaunchKernelGGL(nlm_fused, grid, block, 0, stream, rgb, out);
}